// Round 2
// baseline (46.919 us; speedup 1.0000x reference)
//
#include <hip/hip_runtime.h>
#include <math.h>

#define GRID_RES 128
#define M_TOT (GRID_RES * GRID_RES)
#define N_PTS 4096
#define B_SZ 4
#define KSPLIT 16
// exp(-0.5*d^2/sigma^2), sigma=0.1  ->  exp(-50*d^2)

// ---------------- Phase 1a: Wx[b][n][gx] = exp(-50*(px-gx)^2) ----------------
__global__ __launch_bounds__(256) void wx_kernel(const float* __restrict__ x_c,
                                                 const float* __restrict__ grid_points,
                                                 float* __restrict__ Wx) {
    const int tid = threadIdx.x;
    const int row = blockIdx.x * 2 + (tid >> 7);   // flat (b*N + n), 0..16383
    const int gx  = tid & 127;
    const float px  = x_c[(size_t)row * 2 + 0];
    const float gxv = grid_points[gx];             // grid_x[0][j] = coords[j]
    const float dx  = px - gxv;
    Wx[(size_t)row * GRID_RES + gx] = __expf(-50.0f * dx * dx);
}

// ---- Phase 1b: WyT[b][gy][n] = exp(-50*(py-gy)^2)*mask ; YWyT = WyT * y_c ----
__global__ __launch_bounds__(256) void wy_kernel(const float* __restrict__ x_c,
                                                 const float* __restrict__ y_c,
                                                 const int* __restrict__ mask,
                                                 const float* __restrict__ grid_points,
                                                 float* __restrict__ WyT,
                                                 float* __restrict__ YWyT) {
    const int bg = blockIdx.x;              // b*128 + gy
    const int b  = bg >> 7;
    const int gy = bg & 127;
    const float gyv = grid_points[M_TOT + gy * GRID_RES];  // grid_y[i][0] = coords[i]
    const size_t rowoff = (size_t)bg * N_PTS;
    const size_t inoff  = (size_t)b * N_PTS;
    for (int n = threadIdx.x; n < N_PTS; n += 256) {
        const float py = x_c[(inoff + n) * 2 + 1];
        const float v  = y_c[inoff + n];
        const float mk = (mask[inoff + n] != 0) ? 1.0f : 0.0f;
        const float dy = py - gyv;
        const float wy = __expf(-50.0f * dy * dy) * mk;
        WyT[rowoff + n]  = wy;
        YWyT[rowoff + n] = wy * v;
    }
}

// ------- Phase 2: partial[ks][b][ch][gy][gx] = sum over K-chunk of products ---
__global__ __launch_bounds__(256) void gemm_kernel(const float* __restrict__ Wx,
                                                   const float* __restrict__ WyT,
                                                   const float* __restrict__ YWyT,
                                                   float* __restrict__ partial) {
    const int ks  = blockIdx.x;       // 0..KSPLIT-1, K-chunk of 256
    const int tyb = blockIdx.y;       // 0..3, tile of 32 gy rows
    const int b   = blockIdx.z;       // batch
    const int tid = threadIdx.x;      // 0..255
    const int txi = tid & 31;
    const int tyi = tid >> 5;         // 0..7
    const int cx0 = txi * 4;          // 4 gx columns per thread
    const int r0  = tyi * 4;          // 4 gy rows (within tile) per thread
    const int gy0 = tyb * 32;
    const int n0  = ks * (N_PTS / KSPLIT);   // 256-wide K chunk

    __shared__ float wx_s[64][128];   // 32 KB
    __shared__ float wy_s[32][64];    // 8 KB
    __shared__ float yw_s[32][64];    // 8 KB

    float accd[4][4] = {{0.f}};
    float accw[4][4] = {{0.f}};

    for (int stage = 0; stage < 4; ++stage) {
        const int nb = n0 + stage * 64;
        __syncthreads();
        // stage Wx chunk: 64 rows x 128 cols, contiguous in global -> linear copy
        {
            const float4* src = (const float4*)(Wx + ((size_t)(b * N_PTS + nb)) * GRID_RES);
            float4* dst = (float4*)&wx_s[0][0];
            #pragma unroll
            for (int i = 0; i < 8; ++i) dst[tid + 256 * i] = src[tid + 256 * i];
        }
        // stage WyT / YWyT chunks: 32 rows x 64 cols each (2 float4 per thread per mat)
        {
            const int fi  = tid * 2;          // float4 index, even
            const int row = fi >> 4;          // 16 float4 per 64-float row
            const int col = fi & 15;
            const float4* srcy = (const float4*)(WyT  + ((size_t)(b * GRID_RES + gy0 + row)) * N_PTS + nb);
            const float4* srcv = (const float4*)(YWyT + ((size_t)(b * GRID_RES + gy0 + row)) * N_PTS + nb);
            float4* dy = (float4*)&wy_s[row][0];
            float4* dv = (float4*)&yw_s[row][0];
            dy[col]     = srcy[col];
            dy[col + 1] = srcy[col + 1];
            dv[col]     = srcv[col];
            dv[col + 1] = srcv[col + 1];
        }
        __syncthreads();

        for (int nn = 0; nn < 64; nn += 4) {
            float4 wxv[4], wyv[4], ywv[4];
            #pragma unroll
            for (int j = 0; j < 4; ++j) wxv[j] = *(const float4*)&wx_s[nn + j][cx0];
            #pragma unroll
            for (int i = 0; i < 4; ++i) wyv[i] = *(const float4*)&wy_s[r0 + i][nn];
            #pragma unroll
            for (int i = 0; i < 4; ++i) ywv[i] = *(const float4*)&yw_s[r0 + i][nn];
            #pragma unroll
            for (int i = 0; i < 4; ++i) {
                const float* wyp = (const float*)&wyv[i];
                const float* ywp = (const float*)&ywv[i];
                #pragma unroll
                for (int t = 0; t < 4; ++t) {
                    const float a = wyp[t];
                    const float c = ywp[t];
                    const float* wxp = (const float*)&wxv[t];
                    #pragma unroll
                    for (int j = 0; j < 4; ++j) {
                        accd[i][j] = fmaf(a, wxp[j], accd[i][j]);
                        accw[i][j] = fmaf(c, wxp[j], accw[i][j]);
                    }
                }
            }
        }
    }

    float* pd = partial + (((size_t)ks * B_SZ + b) * 2 + 0) * M_TOT;
    float* pw = partial + (((size_t)ks * B_SZ + b) * 2 + 1) * M_TOT;
    #pragma unroll
    for (int i = 0; i < 4; ++i) {
        const int row = gy0 + r0 + i;
        *(float4*)&pd[row * GRID_RES + cx0] =
            make_float4(accd[i][0], accd[i][1], accd[i][2], accd[i][3]);
        *(float4*)&pw[row * GRID_RES + cx0] =
            make_float4(accw[i][0], accw[i][1], accw[i][2], accw[i][3]);
    }
}

// ------------- Phase 3: reduce K-partials + normalize ------------------------
__global__ __launch_bounds__(256) void reduce_kernel(const float* __restrict__ partial,
                                                     float* __restrict__ out) {
    const int idx = blockIdx.x * 256 + threadIdx.x;   // 0 .. B*M-1
    const int b = idx >> 14;
    const int m = idx & (M_TOT - 1);
    float d = 0.f, w = 0.f;
    #pragma unroll
    for (int ks = 0; ks < KSPLIT; ++ks) {
        d += partial[(((size_t)ks * B_SZ + b) * 2 + 0) * M_TOT + m];
        w += partial[(((size_t)ks * B_SZ + b) * 2 + 1) * M_TOT + m];
    }
    out[((size_t)b * 2 + 0) * M_TOT + m] = d;
    out[((size_t)b * 2 + 1) * M_TOT + m] = w / (d + 1e-5f);
}

extern "C" void kernel_launch(void* const* d_in, const int* in_sizes, int n_in,
                              void* d_out, int out_size, void* d_ws, size_t ws_size,
                              hipStream_t stream) {
    const float* x_c  = (const float*)d_in[0];   // (B,N,2)
    const float* y_c  = (const float*)d_in[1];   // (B,N,1)
    const float* gp   = (const float*)d_in[2];   // (2,M)
    const int* mask   = (const int*)d_in[3];     // (B,N) bool -> int32
    float* out = (float*)d_out;                  // (B,2,128,128)

    float* Wx      = (float*)d_ws;                                    // B*N*128  (8MB)
    float* WyT     = Wx   + (size_t)B_SZ * N_PTS * GRID_RES;          // B*128*N  (8MB)
    float* YWyT    = WyT  + (size_t)B_SZ * GRID_RES * N_PTS;          // B*128*N  (8MB)
    float* partial = YWyT + (size_t)B_SZ * GRID_RES * N_PTS;          // 16*B*2*M (8MB)

    wx_kernel<<<B_SZ * N_PTS / 2, 256, 0, stream>>>(x_c, gp, Wx);
    wy_kernel<<<B_SZ * GRID_RES, 256, 0, stream>>>(x_c, y_c, mask, gp, WyT, YWyT);
    gemm_kernel<<<dim3(KSPLIT, GRID_RES / 32, B_SZ), 256, 0, stream>>>(Wx, WyT, YWyT, partial);
    reduce_kernel<<<B_SZ * M_TOT / 256, 256, 0, stream>>>(partial, out);
}